// Round 11
// baseline (154.699 us; speedup 1.0000x reference)
//
#include <hip/hip_runtime.h>
#include <cstdint>
#include <cstddef>

// Problem constants
#define BATCH 8
#define CCH   512     // channels
#define SSP   1024    // spatial = 32*32
#define NH    8       // heads
#define DH    64      // head dim
#define O3    1536    // 3*C

typedef __bf16 bf16x8 __attribute__((ext_vector_type(8)));
typedef float  f32x4  __attribute__((ext_vector_type(4)));

__device__ __forceinline__ unsigned short f2bf(float f) {
    unsigned u = __builtin_bit_cast(unsigned, f);
    unsigned r = u + 0x7fffu + ((u >> 16) & 1u);   // RNE
    return (unsigned short)(r >> 16);
}

// pack two fp32 -> one dword of 2 bf16 (round-half-up), single v_perm
__device__ __forceinline__ unsigned pk2bf(float lo, float hi) {
    unsigned ul = __builtin_bit_cast(unsigned, lo) + 0x8000u;
    unsigned uh = __builtin_bit_cast(unsigned, hi) + 0x8000u;
    return __builtin_amdgcn_perm(uh, ul, 0x07060302u);
}

__device__ __forceinline__ bf16x8 ld8(const unsigned short* p) {
    uint4 u = *(const uint4*)p;
    return __builtin_bit_cast(bf16x8, u);
}

// async global->LDS, 16B per lane; LDS dest is wave-uniform base + lane*16
__device__ __forceinline__ void glls16(const void* g, void* l) {
    __builtin_amdgcn_global_load_lds(
        (const __attribute__((address_space(1))) unsigned*)g,
        (__attribute__((address_space(3))) unsigned*)l, 16, 0, 0);
}

// ---------------------------------------------------------------------------
// Fused: blocks [0,256) do GroupNorm+transpose; blocks [256,1280) convert the
// two weight matrices fp32->bf16.
__global__ __launch_bounds__(256) void gn_wconv(const float* __restrict__ x,
                                                const float* __restrict__ gw,
                                                const float* __restrict__ gb,
                                                unsigned short* __restrict__ xnt,
                                                const float* __restrict__ s1,
                                                unsigned short* __restrict__ d1, int n1,
                                                const float* __restrict__ s2,
                                                unsigned short* __restrict__ d2) {
    int t = threadIdx.x;
    if (blockIdx.x >= 256) {
        int i = (blockIdx.x - 256) * 256 + t;
        const float4* sp;
        ushort4* dp;
        if (i < n1) { sp = (const float4*)s1 + i; dp = (ushort4*)d1 + i; }
        else        { sp = (const float4*)s2 + (i - n1); dp = (ushort4*)d2 + (i - n1); }
        float4 v = *sp;
        ushort4 o;
        o.x = f2bf(v.x); o.y = f2bf(v.y); o.z = f2bf(v.z); o.w = f2bf(v.w);
        *dp = o;
        return;
    }

    int blk = blockIdx.x;
    int b = blk >> 5, g = blk & 31;
    const float4* xp = (const float4*)(x + (size_t)(b * CCH + g * 16) * SSP);

    float4 vals[16];
    float sum = 0.f, ss = 0.f;
#pragma unroll
    for (int i = 0; i < 16; i++) {
        float4 v = xp[i * 256 + t];
        vals[i] = v;
        sum += (v.x + v.y) + (v.z + v.w);
        ss  += (v.x * v.x + v.y * v.y) + (v.z * v.z + v.w * v.w);
    }
#pragma unroll
    for (int o = 32; o; o >>= 1) {
        sum += __shfl_xor(sum, o, 64);
        ss  += __shfl_xor(ss,  o, 64);
    }
    __shared__ float red[8];
    if ((t & 63) == 0) { red[(t >> 6) * 2] = sum; red[(t >> 6) * 2 + 1] = ss; }
    __syncthreads();
    sum = red[0] + red[2] + red[4] + red[6];
    ss  = red[1] + red[3] + red[5] + red[7];

    float mean = sum * (1.f / 16384.f);
    float var  = ss * (1.f / 16384.f) - mean * mean;
    float rstd = rsqrtf(var + 1e-5f);

    __shared__ unsigned short tile[16][1032];
#pragma unroll
    for (int i = 0; i < 16; i++) {
        int f4 = i * 256 + t;
        int c = f4 >> 8;
        int s = (f4 & 255) * 4;
        float wsc = gw[g * 16 + c] * rstd;
        float bia = gb[g * 16 + c] - mean * wsc;
        float4 v = vals[i];
        tile[c][s + 0] = f2bf(v.x * wsc + bia);
        tile[c][s + 1] = f2bf(v.y * wsc + bia);
        tile[c][s + 2] = f2bf(v.z * wsc + bia);
        tile[c][s + 3] = f2bf(v.w * wsc + bia);
    }
    __syncthreads();

    int c2 = (t & 7) * 2, sr = t >> 3;
    unsigned short* outbase = xnt + (size_t)b * SSP * CCH + g * 16 + c2;
#pragma unroll
    for (int i = 0; i < 32; i++) {
        int s = i * 32 + sr;
        unsigned v = (unsigned)tile[c2][s] | ((unsigned)tile[c2 + 1][s] << 16);
        *(unsigned*)(outbase + (size_t)s * CCH) = v;
    }
}

// ---------------------------------------------------------------------------
// NT GEMM 128x128, BK=64, global_load_lds(16B) + XOR bank swizzle.
// qkv: col<1024 -> qkv_t[b][s][o] bf16 (Q cols pre-scaled by 0.125*log2e for
// the max-free softmax); col>=1024 (V) -> v_t[bz*512+ch][s] bf16.
__global__ __launch_bounds__(256) void gemm_qkv(const unsigned short* __restrict__ Aall,
                                                const unsigned short* __restrict__ Bw,
                                                const float* __restrict__ bias,
                                                unsigned short* __restrict__ Call,
                                                unsigned short* __restrict__ vtout) {
    const int K = 512;
    int bz = blockIdx.z;
    const unsigned short* A = Aall + (size_t)bz * SSP * CCH;
    int m0 = blockIdx.x * 128, n0 = blockIdx.y * 128;

    __shared__ unsigned short As[128 * 64], Bs[128 * 64];
    int t = threadIdx.x, wave = t >> 6, lane = t & 63;
    int quad = lane >> 4, l16 = lane & 15;
    int wm = (wave & 1) * 64, wn = (wave >> 1) * 64;

    int lrow = lane >> 3;
    int lc   = ((lane & 7) - lrow) & 7;
    const unsigned short* Ag = A  + (size_t)(m0 + wave * 32 + lrow) * K + lc * 8;
    const unsigned short* Bg = Bw + (size_t)(n0 + wave * 32 + lrow) * K + lc * 8;
    unsigned short* Asw = As + wave * 2048;
    unsigned short* Bsw = Bs + wave * 2048;

    f32x4 acc[4][4];
#pragma unroll
    for (int i = 0; i < 4; i++)
#pragma unroll
        for (int j = 0; j < 4; j++) acc[i][j] = f32x4{0.f, 0.f, 0.f, 0.f};

    int rowA = (wm + l16) * 64, rowB = (wn + l16) * 64;
    int cph[2];
#pragma unroll
    for (int kc = 0; kc < 2; kc++) cph[kc] = ((quad + 4 * kc + l16) & 7) * 8;

    for (int k0 = 0; k0 < K; k0 += 64) {
        __syncthreads();
#pragma unroll
        for (int i = 0; i < 4; i++) {
            glls16(Ag + (size_t)i * 8 * K + k0, Asw + i * 512);
            glls16(Bg + (size_t)i * 8 * K + k0, Bsw + i * 512);
        }
        __syncthreads();
#pragma unroll
        for (int kc = 0; kc < 2; kc++) {
            bf16x8 af[4], bfr[4];
#pragma unroll
            for (int i = 0; i < 4; i++) {
                af[i]  = ld8(As + rowA + i * 1024 + cph[kc]);
                bfr[i] = ld8(Bs + rowB + i * 1024 + cph[kc]);
            }
#pragma unroll
            for (int i = 0; i < 4; i++)
#pragma unroll
                for (int j = 0; j < 4; j++)
                    acc[i][j] = __builtin_amdgcn_mfma_f32_16x16x32_bf16(af[i], bfr[j], acc[i][j], 0, 0, 0);
        }
    }

    if (n0 < 1024) {
        // Q columns (<512) carry the softmax scale so attn's exp2 needs no mul
        float scl = (n0 < 512) ? 0.18033688011f : 1.0f;   // 0.125 * log2(e)
        unsigned short* Cp = Call + (size_t)bz * SSP * O3;
#pragma unroll
        for (int i = 0; i < 4; i++)
#pragma unroll
            for (int j = 0; j < 4; j++) {
                int col = n0 + wn + j * 16 + l16;
                float bv = bias[col];
#pragma unroll
                for (int r = 0; r < 4; r++) {
                    int row = m0 + wm + i * 16 + quad * 4 + r;
                    Cp[(size_t)row * O3 + col] = f2bf((acc[i][j][r] + bv) * scl);
                }
            }
    } else {
#pragma unroll
        for (int j = 0; j < 4; j++) {
            int col = n0 + wn + j * 16 + l16;
            float bv = bias[col];
            unsigned short* vp = vtout + ((size_t)bz * 512 + (col - 1024)) * SSP;
#pragma unroll
            for (int i = 0; i < 4; i++) {
                int s = m0 + wm + i * 16 + quad * 4;
                uint2 d;
                d.x = pk2bf(acc[i][j][0] + bv, acc[i][j][1] + bv);
                d.y = pk2bf(acc[i][j][2] + bv, acc[i][j][3] + bv);
                *(uint2*)(vp + s) = d;
            }
        }
    }
}

// proj: out[b][o][s] = x + proj_w . o_t + proj_b. 64x128 tiles, 512 blocks.
__global__ __launch_bounds__(256) void gemm_proj(const unsigned short* __restrict__ Pw,
                                                 const unsigned short* __restrict__ Oall,
                                                 const float* __restrict__ bias,
                                                 const float* __restrict__ xres,
                                                 float* __restrict__ Out) {
    const int K = 512;
    int bz = blockIdx.z;
    const unsigned short* Bv = Oall + (size_t)bz * SSP * CCH;
    int m0 = blockIdx.x * 64, n0 = blockIdx.y * 128;

    __shared__ unsigned short As[64 * 64], Bs[128 * 64];
    int t = threadIdx.x, wave = t >> 6, lane = t & 63;
    int quad = lane >> 4, l16 = lane & 15;
    int wr = (wave & 1) * 32, wc = (wave >> 1) * 64;

    int lrow = lane >> 3;
    int lc   = ((lane & 7) - lrow) & 7;
    const unsigned short* Ag = Pw + (size_t)(m0 + wave * 16 + lrow) * K + lc * 8;
    const unsigned short* Bg = Bv + (size_t)(n0 + wave * 32 + lrow) * K + lc * 8;
    unsigned short* Asw = As + wave * 1024;
    unsigned short* Bsw = Bs + wave * 2048;

    f32x4 acc[2][4];
#pragma unroll
    for (int i = 0; i < 2; i++)
#pragma unroll
        for (int j = 0; j < 4; j++) acc[i][j] = f32x4{0.f, 0.f, 0.f, 0.f};

    int rowA = (wr + l16) * 64, rowB = (wc + l16) * 64;
    int cph[2];
#pragma unroll
    for (int kc = 0; kc < 2; kc++) cph[kc] = ((quad + 4 * kc + l16) & 7) * 8;

    for (int k0 = 0; k0 < K; k0 += 64) {
        __syncthreads();
#pragma unroll
        for (int i = 0; i < 2; i++)
            glls16(Ag + (size_t)i * 8 * K + k0, Asw + i * 512);
#pragma unroll
        for (int i = 0; i < 4; i++)
            glls16(Bg + (size_t)i * 8 * K + k0, Bsw + i * 512);
        __syncthreads();
#pragma unroll
        for (int kc = 0; kc < 2; kc++) {
            bf16x8 af[2], bfr[4];
#pragma unroll
            for (int i = 0; i < 2; i++) af[i]  = ld8(As + rowA + i * 1024 + cph[kc]);
#pragma unroll
            for (int j = 0; j < 4; j++) bfr[j] = ld8(Bs + rowB + j * 1024 + cph[kc]);
#pragma unroll
            for (int i = 0; i < 2; i++)
#pragma unroll
                for (int j = 0; j < 4; j++)
                    acc[i][j] = __builtin_amdgcn_mfma_f32_16x16x32_bf16(af[i], bfr[j], acc[i][j], 0, 0, 0);
        }
    }
#pragma unroll
    for (int i = 0; i < 2; i++)
#pragma unroll
        for (int j = 0; j < 4; j++) {
            int col = n0 + wc + j * 16 + l16;
#pragma unroll
            for (int r = 0; r < 4; r++) {
                int row = m0 + wr + i * 16 + quad * 4 + r;
                size_t idx = (size_t)bz * CCH * SSP + (size_t)row * SSP + col;
                Out[idx] = xres[idx] + acc[i][j][r] + bias[row];
            }
        }
}

// ---------------------------------------------------------------------------
// Flash attention v9 = v8's math with 128-THREAD blocks (2 waves):
//  - Same 2 i-sets/wave ILP (each kf/vf LDS read feeds 2 MFMAs).
//  - 64 q-rows/block, grid 1024, LDS 40 KB -> 4 blocks/CU: same 8 waves/CU
//    as v8 but barriers now rendezvous only 2 waves (4 independent barrier
//    groups per CU instead of 2) -> halves the barrier convoy stall.
//  - glls DMA double-buffer, 1 barrier/iter, max-free softmax (Q pre-scaled),
//    per-lane deferred l-reduction. No per-wave global K/V (v7 failure),
//    no VGPR tile prefetch (R3 failure).
__global__ __launch_bounds__(128, 2) void attn(const unsigned short* __restrict__ qkvt,
                                               const unsigned short* __restrict__ vt,
                                               unsigned short* __restrict__ ot) {
    int blk = blockIdx.x;                    // 1024 blocks
    int xcd = blk & 7, jj = blk >> 3;        // 128 per XCD
    int bh = xcd * 8 + (jj >> 4);            // 8 heads per XCD (L2 locality)
    int i0 = (jj & 15) * 64;                 // 16 i-chunks of 64 rows
    int b = bh >> 3, h = bh & 7;

    __shared__ unsigned short KsD[2][64 * 64];      // [j][c] swizzled, 8 KB each
    __shared__ unsigned short VsD[2][64 * 64];      // [c][j] swizzled, 8 KB each
    __shared__ unsigned short PsD[2][2][16 * 64];   // [wave][iset] P^T, 8 KB

    int t = threadIdx.x, wave = t >> 6, lane = t & 63;
    int quad = lane >> 4, l16 = lane & 15;

    // Q fragments (B-operand) for the wave's two i-sets
    bf16x8 qf[2][2];   // [kc][iset]
#pragma unroll
    for (int is = 0; is < 2; is++) {
        const unsigned short* qp =
            qkvt + ((size_t)b * SSP + i0 + wave * 32 + is * 16 + l16) * O3 + h * DH + quad * 8;
        qf[0][is] = ld8(qp);
        qf[1][is] = ld8(qp + 32);
    }

    f32x4 Oa[2][4];
#pragma unroll
    for (int is = 0; is < 2; is++)
#pragma unroll
        for (int i = 0; i < 4; i++) Oa[is][i] = f32x4{0.f, 0.f, 0.f, 0.f};
    float l_acc[2] = {0.f, 0.f};

    // staging: 64-row tiles, 8 glls per tile, 4 per wave (2 waves)
    int lrow8 = lane >> 3, lc8 = ((lane & 7) - lrow8) & 7;
    const unsigned short* kga = qkvt + (size_t)b * SSP * O3 + CCH + h * DH;
    const unsigned short* vga = vt + (size_t)bh * DH * SSP;
    size_t koff[4];
    int voff[4], lds_off[4];
#pragma unroll
    for (int p = 0; p < 4; p++) {
        int row = wave * 32 + p * 8 + lrow8;
        koff[p] = (size_t)row * O3 + lc8 * 8;
        voff[p] = row * SSP + lc8 * 8;
        lds_off[p] = (wave * 32 + p * 8) * 64;
    }

    // prologue: stage tile 0 into buffer 0
#pragma unroll
    for (int p = 0; p < 4; p++) glls16(kga + koff[p], &KsD[0][lds_off[p]]);
#pragma unroll
    for (int p = 0; p < 4; p++) glls16(vga + voff[p], &VsD[0][lds_off[p]]);
    __syncthreads();

    for (int jb = 0; jb < 16; jb++) {
        int cur = jb & 1;
        if (jb < 15) {               // prefetch tile jb+1 (drains at barrier)
            int nxt = cur ^ 1;
            size_t j1k = (size_t)(jb + 1) * 64 * O3;
            int j1v = (jb + 1) * 64;
#pragma unroll
            for (int p = 0; p < 4; p++) glls16(kga + j1k + koff[p], &KsD[nxt][lds_off[p]]);
#pragma unroll
            for (int p = 0; p < 4; p++) glls16(vga + j1v + voff[p], &VsD[nxt][lds_off[p]]);
        }
        const unsigned short* ks = KsD[cur];
        const unsigned short* vs = VsD[cur];

        // load K fragments ONCE, feed both i-sets
        bf16x8 kf[2][4];
#pragma unroll
        for (int kc = 0; kc < 2; kc++)
#pragma unroll
            for (int tj = 0; tj < 4; tj++) {
                int row = tj * 16 + l16;
                kf[kc][tj] = ld8(ks + row * 64 + ((kc * 4 + quad + l16) & 7) * 8);
            }

        // S^T for both i-sets
        f32x4 sc0[4], sc1[4];
#pragma unroll
        for (int tj = 0; tj < 4; tj++) { sc0[tj] = f32x4{0.f,0.f,0.f,0.f}; sc1[tj] = f32x4{0.f,0.f,0.f,0.f}; }
#pragma unroll
        for (int kc = 0; kc < 2; kc++)
#pragma unroll
            for (int tj = 0; tj < 4; tj++) {
                sc0[tj] = __builtin_amdgcn_mfma_f32_16x16x32_bf16(kf[kc][tj], qf[kc][0], sc0[tj], 0, 0, 0);
                sc1[tj] = __builtin_amdgcn_mfma_f32_16x16x32_bf16(kf[kc][tj], qf[kc][1], sc1[tj], 0, 0, 0);
            }

        // max-free softmax + P pack for both i-sets (wave-local, no barrier)
        unsigned short* Ps0 = PsD[wave][0];
        unsigned short* Ps1 = PsD[wave][1];
#pragma unroll
        for (int tj = 0; tj < 4; tj++) {
#pragma unroll
            for (int r = 0; r < 4; r++) {
                float p0 = __builtin_amdgcn_exp2f(sc0[tj][r]);
                float p1 = __builtin_amdgcn_exp2f(sc1[tj][r]);
                sc0[tj][r] = p0; l_acc[0] += p0;
                sc1[tj][r] = p1; l_acc[1] += p1;
            }
            int phys = (tj * 2 + (quad >> 1) + l16) & 7;
            uint2 d0, d1;
            d0.x = pk2bf(sc0[tj][0], sc0[tj][1]);
            d0.y = pk2bf(sc0[tj][2], sc0[tj][3]);
            d1.x = pk2bf(sc1[tj][0], sc1[tj][1]);
            d1.y = pk2bf(sc1[tj][2], sc1[tj][3]);
            *(uint2*)(Ps0 + l16 * 64 + phys * 8 + (quad & 1) * 4) = d0;
            *(uint2*)(Ps1 + l16 * 64 + phys * 8 + (quad & 1) * 4) = d1;
        }

        // O^T += V^T . P^T; each vf load feeds both i-sets
#pragma unroll
        for (int kj = 0; kj < 2; kj++) {
            int pch = ((kj * 4 + quad + l16) & 7) * 8;
            bf16x8 pf0 = ld8(Ps0 + l16 * 64 + pch);
            bf16x8 pf1 = ld8(Ps1 + l16 * 64 + pch);
#pragma unroll
            for (int tc = 0; tc < 4; tc++) {
                int row = tc * 16 + l16;
                bf16x8 vf = ld8(vs + row * 64 + ((kj * 4 + quad + l16) & 7) * 8);
                Oa[0][tc] = __builtin_amdgcn_mfma_f32_16x16x32_bf16(vf, pf0, Oa[0][tc], 0, 0, 0);
                Oa[1][tc] = __builtin_amdgcn_mfma_f32_16x16x32_bf16(vf, pf1, Oa[1][tc], 0, 0, 0);
            }
        }

        __syncthreads();   // drains prefetch DMA + protects buffer swap
    }

    // deferred l-reduction + write-out per i-set
#pragma unroll
    for (int is = 0; is < 2; is++) {
        float l = l_acc[is];
        l += __shfl_xor(l, 16, 64);
        l += __shfl_xor(l, 32, 64);
        float rl = 1.f / l;
        int i = i0 + wave * 32 + is * 16 + l16;
        unsigned short* ob = ot + ((size_t)b * SSP + i) * CCH + h * DH;
#pragma unroll
        for (int tc = 0; tc < 4; tc++) {
            uint2 d;
            d.x = pk2bf(Oa[is][tc][0] * rl, Oa[is][tc][1] * rl);
            d.y = pk2bf(Oa[is][tc][2] * rl, Oa[is][tc][3] * rl);
            *(uint2*)(ob + tc * 16 + quad * 4) = d;
        }
    }
}

// ---------------------------------------------------------------------------
extern "C" void kernel_launch(void* const* d_in, const int* in_sizes, int n_in,
                              void* d_out, int out_size, void* d_ws, size_t ws_size,
                              hipStream_t stream) {
    const float* x      = (const float*)d_in[0];
    const float* gn_w   = (const float*)d_in[1];
    const float* gn_b   = (const float*)d_in[2];
    const float* qkv_w  = (const float*)d_in[3];
    const float* qkv_b  = (const float*)d_in[4];
    const float* proj_w = (const float*)d_in[5];
    const float* proj_b = (const float*)d_in[6];
    float* out = (float*)d_out;

    char* ws = (char*)d_ws;
    unsigned short* xnt   = (unsigned short*)(ws);                 // 8 MB  xn_t[b][s][c]
    unsigned short* qw_bf = (unsigned short*)(ws + 8388608);       // 1.5MB qkv_w bf16
    unsigned short* pw_bf = (unsigned short*)(ws + 9961472);       // 0.5MB proj_w bf16
    unsigned short* qkvt  = (unsigned short*)(ws + 10485760);      // 24 MB qkv_t[b][s][3C] (Q,K used)
    unsigned short* vt    = (unsigned short*)(ws + 35651584);      // 8 MB  v_t[bh*64+c][j]
    unsigned short* otb   = (unsigned short*)(ws + 44040192);      // 8 MB  o_t[b][s][c]

    gn_wconv<<<dim3(1280), dim3(256), 0, stream>>>(x, gn_w, gn_b, xnt,
                                                   qkv_w, qw_bf, 196608, proj_w, pw_bf);
    gemm_qkv<<<dim3(8, 12, 8), dim3(256), 0, stream>>>(xnt, qw_bf, qkv_b, qkvt, vt);
    attn<<<dim3(1024), dim3(128), 0, stream>>>(qkvt, vt, otb);
    gemm_proj<<<dim3(8, 8, 8), dim3(256), 0, stream>>>(pw_bf, otb, proj_b, x, out);
}

// Round 12
// 153.313 us; speedup vs baseline: 1.0090x; 1.0090x over previous
//
#include <hip/hip_runtime.h>
#include <cstdint>
#include <cstddef>

// Problem constants
#define BATCH 8
#define CCH   512     // channels
#define SSP   1024    // spatial = 32*32
#define NH    8       // heads
#define DH    64      // head dim
#define O3    1536    // 3*C

typedef __bf16 bf16x8 __attribute__((ext_vector_type(8)));
typedef float  f32x4  __attribute__((ext_vector_type(4)));

__device__ __forceinline__ unsigned short f2bf(float f) {
    unsigned u = __builtin_bit_cast(unsigned, f);
    unsigned r = u + 0x7fffu + ((u >> 16) & 1u);   // RNE
    return (unsigned short)(r >> 16);
}

// pack two fp32 -> one dword of 2 bf16 (round-half-up), single v_perm
__device__ __forceinline__ unsigned pk2bf(float lo, float hi) {
    unsigned ul = __builtin_bit_cast(unsigned, lo) + 0x8000u;
    unsigned uh = __builtin_bit_cast(unsigned, hi) + 0x8000u;
    return __builtin_amdgcn_perm(uh, ul, 0x07060302u);
}

__device__ __forceinline__ bf16x8 ld8(const unsigned short* p) {
    uint4 u = *(const uint4*)p;
    return __builtin_bit_cast(bf16x8, u);
}

// async global->LDS, 16B per lane; LDS dest is wave-uniform base + lane*16
__device__ __forceinline__ void glls16(const void* g, void* l) {
    __builtin_amdgcn_global_load_lds(
        (const __attribute__((address_space(1))) unsigned*)g,
        (__attribute__((address_space(3))) unsigned*)l, 16, 0, 0);
}

// ---------------------------------------------------------------------------
// Fused: blocks [0,256) do GroupNorm+transpose; blocks [256,1280) convert the
// two weight matrices fp32->bf16.
__global__ __launch_bounds__(256) void gn_wconv(const float* __restrict__ x,
                                                const float* __restrict__ gw,
                                                const float* __restrict__ gb,
                                                unsigned short* __restrict__ xnt,
                                                const float* __restrict__ s1,
                                                unsigned short* __restrict__ d1, int n1,
                                                const float* __restrict__ s2,
                                                unsigned short* __restrict__ d2) {
    int t = threadIdx.x;
    if (blockIdx.x >= 256) {
        int i = (blockIdx.x - 256) * 256 + t;
        const float4* sp;
        ushort4* dp;
        if (i < n1) { sp = (const float4*)s1 + i; dp = (ushort4*)d1 + i; }
        else        { sp = (const float4*)s2 + (i - n1); dp = (ushort4*)d2 + (i - n1); }
        float4 v = *sp;
        ushort4 o;
        o.x = f2bf(v.x); o.y = f2bf(v.y); o.z = f2bf(v.z); o.w = f2bf(v.w);
        *dp = o;
        return;
    }

    int blk = blockIdx.x;
    int b = blk >> 5, g = blk & 31;
    const float4* xp = (const float4*)(x + (size_t)(b * CCH + g * 16) * SSP);

    float4 vals[16];
    float sum = 0.f, ss = 0.f;
#pragma unroll
    for (int i = 0; i < 16; i++) {
        float4 v = xp[i * 256 + t];
        vals[i] = v;
        sum += (v.x + v.y) + (v.z + v.w);
        ss  += (v.x * v.x + v.y * v.y) + (v.z * v.z + v.w * v.w);
    }
#pragma unroll
    for (int o = 32; o; o >>= 1) {
        sum += __shfl_xor(sum, o, 64);
        ss  += __shfl_xor(ss,  o, 64);
    }
    __shared__ float red[8];
    if ((t & 63) == 0) { red[(t >> 6) * 2] = sum; red[(t >> 6) * 2 + 1] = ss; }
    __syncthreads();
    sum = red[0] + red[2] + red[4] + red[6];
    ss  = red[1] + red[3] + red[5] + red[7];

    float mean = sum * (1.f / 16384.f);
    float var  = ss * (1.f / 16384.f) - mean * mean;
    float rstd = rsqrtf(var + 1e-5f);

    __shared__ unsigned short tile[16][1032];
#pragma unroll
    for (int i = 0; i < 16; i++) {
        int f4 = i * 256 + t;
        int c = f4 >> 8;
        int s = (f4 & 255) * 4;
        float wsc = gw[g * 16 + c] * rstd;
        float bia = gb[g * 16 + c] - mean * wsc;
        float4 v = vals[i];
        tile[c][s + 0] = f2bf(v.x * wsc + bia);
        tile[c][s + 1] = f2bf(v.y * wsc + bia);
        tile[c][s + 2] = f2bf(v.z * wsc + bia);
        tile[c][s + 3] = f2bf(v.w * wsc + bia);
    }
    __syncthreads();

    // transposed write: 4 channels/thread -> 8B stores (was 2 ch / 4B)
    int c4 = (t & 3) * 4, sr = t >> 2;
    unsigned short* outbase = xnt + (size_t)b * SSP * CCH + g * 16 + c4;
#pragma unroll
    for (int i = 0; i < 16; i++) {
        int s = i * 64 + sr;
        uint2 v;
        v.x = (unsigned)tile[c4 + 0][s] | ((unsigned)tile[c4 + 1][s] << 16);
        v.y = (unsigned)tile[c4 + 2][s] | ((unsigned)tile[c4 + 3][s] << 16);
        *(uint2*)(outbase + (size_t)s * CCH) = v;
    }
}

// ---------------------------------------------------------------------------
// NT GEMM 128x128, BK=64, global_load_lds(16B) + XOR bank swizzle.
// qkv: col<1024 -> qkv_t[b][s][o] bf16 (Q cols pre-scaled by 0.125*log2e for
// the max-free softmax); col>=1024 (V) -> v_t[bz*512+ch][s] bf16.
__global__ __launch_bounds__(256) void gemm_qkv(const unsigned short* __restrict__ Aall,
                                                const unsigned short* __restrict__ Bw,
                                                const float* __restrict__ bias,
                                                unsigned short* __restrict__ Call,
                                                unsigned short* __restrict__ vtout) {
    const int K = 512;
    int bz = blockIdx.z;
    const unsigned short* A = Aall + (size_t)bz * SSP * CCH;
    int m0 = blockIdx.x * 128, n0 = blockIdx.y * 128;

    __shared__ unsigned short As[128 * 64], Bs[128 * 64];
    int t = threadIdx.x, wave = t >> 6, lane = t & 63;
    int quad = lane >> 4, l16 = lane & 15;
    int wm = (wave & 1) * 64, wn = (wave >> 1) * 64;

    int lrow = lane >> 3;
    int lc   = ((lane & 7) - lrow) & 7;
    const unsigned short* Ag = A  + (size_t)(m0 + wave * 32 + lrow) * K + lc * 8;
    const unsigned short* Bg = Bw + (size_t)(n0 + wave * 32 + lrow) * K + lc * 8;
    unsigned short* Asw = As + wave * 2048;
    unsigned short* Bsw = Bs + wave * 2048;

    f32x4 acc[4][4];
#pragma unroll
    for (int i = 0; i < 4; i++)
#pragma unroll
        for (int j = 0; j < 4; j++) acc[i][j] = f32x4{0.f, 0.f, 0.f, 0.f};

    int rowA = (wm + l16) * 64, rowB = (wn + l16) * 64;
    int cph[2];
#pragma unroll
    for (int kc = 0; kc < 2; kc++) cph[kc] = ((quad + 4 * kc + l16) & 7) * 8;

    for (int k0 = 0; k0 < K; k0 += 64) {
        __syncthreads();
#pragma unroll
        for (int i = 0; i < 4; i++) {
            glls16(Ag + (size_t)i * 8 * K + k0, Asw + i * 512);
            glls16(Bg + (size_t)i * 8 * K + k0, Bsw + i * 512);
        }
        __syncthreads();
#pragma unroll
        for (int kc = 0; kc < 2; kc++) {
            bf16x8 af[4], bfr[4];
#pragma unroll
            for (int i = 0; i < 4; i++) {
                af[i]  = ld8(As + rowA + i * 1024 + cph[kc]);
                bfr[i] = ld8(Bs + rowB + i * 1024 + cph[kc]);
            }
#pragma unroll
            for (int i = 0; i < 4; i++)
#pragma unroll
                for (int j = 0; j < 4; j++)
                    acc[i][j] = __builtin_amdgcn_mfma_f32_16x16x32_bf16(af[i], bfr[j], acc[i][j], 0, 0, 0);
        }
    }

    if (n0 < 1024) {
        // Q columns (<512) carry the softmax scale so attn's exp2 needs no mul
        float scl = (n0 < 512) ? 0.18033688011f : 1.0f;   // 0.125 * log2(e)
        unsigned short* Cp = Call + (size_t)bz * SSP * O3;
#pragma unroll
        for (int i = 0; i < 4; i++)
#pragma unroll
            for (int j = 0; j < 4; j++) {
                int col = n0 + wn + j * 16 + l16;
                float bv = bias[col];
#pragma unroll
                for (int r = 0; r < 4; r++) {
                    int row = m0 + wm + i * 16 + quad * 4 + r;
                    Cp[(size_t)row * O3 + col] = f2bf((acc[i][j][r] + bv) * scl);
                }
            }
    } else {
#pragma unroll
        for (int j = 0; j < 4; j++) {
            int col = n0 + wn + j * 16 + l16;
            float bv = bias[col];
            unsigned short* vp = vtout + ((size_t)bz * 512 + (col - 1024)) * SSP;
#pragma unroll
            for (int i = 0; i < 4; i++) {
                int s = m0 + wm + i * 16 + quad * 4;
                uint2 d;
                d.x = pk2bf(acc[i][j][0] + bv, acc[i][j][1] + bv);
                d.y = pk2bf(acc[i][j][2] + bv, acc[i][j][3] + bv);
                *(uint2*)(vp + s) = d;
            }
        }
    }
}

// proj: out[b][o][s] = x + proj_w . o_t + proj_b. 64x128 tiles, 512 blocks.
__global__ __launch_bounds__(256) void gemm_proj(const unsigned short* __restrict__ Pw,
                                                 const unsigned short* __restrict__ Oall,
                                                 const float* __restrict__ bias,
                                                 const float* __restrict__ xres,
                                                 float* __restrict__ Out) {
    const int K = 512;
    int bz = blockIdx.z;
    const unsigned short* Bv = Oall + (size_t)bz * SSP * CCH;
    int m0 = blockIdx.x * 64, n0 = blockIdx.y * 128;

    __shared__ unsigned short As[64 * 64], Bs[128 * 64];
    int t = threadIdx.x, wave = t >> 6, lane = t & 63;
    int quad = lane >> 4, l16 = lane & 15;
    int wr = (wave & 1) * 32, wc = (wave >> 1) * 64;

    int lrow = lane >> 3;
    int lc   = ((lane & 7) - lrow) & 7;
    const unsigned short* Ag = Pw + (size_t)(m0 + wave * 16 + lrow) * K + lc * 8;
    const unsigned short* Bg = Bv + (size_t)(n0 + wave * 32 + lrow) * K + lc * 8;
    unsigned short* Asw = As + wave * 1024;
    unsigned short* Bsw = Bs + wave * 2048;

    f32x4 acc[2][4];
#pragma unroll
    for (int i = 0; i < 2; i++)
#pragma unroll
        for (int j = 0; j < 4; j++) acc[i][j] = f32x4{0.f, 0.f, 0.f, 0.f};

    int rowA = (wr + l16) * 64, rowB = (wc + l16) * 64;
    int cph[2];
#pragma unroll
    for (int kc = 0; kc < 2; kc++) cph[kc] = ((quad + 4 * kc + l16) & 7) * 8;

    for (int k0 = 0; k0 < K; k0 += 64) {
        __syncthreads();
#pragma unroll
        for (int i = 0; i < 2; i++)
            glls16(Ag + (size_t)i * 8 * K + k0, Asw + i * 512);
#pragma unroll
        for (int i = 0; i < 4; i++)
            glls16(Bg + (size_t)i * 8 * K + k0, Bsw + i * 512);
        __syncthreads();
#pragma unroll
        for (int kc = 0; kc < 2; kc++) {
            bf16x8 af[2], bfr[4];
#pragma unroll
            for (int i = 0; i < 2; i++) af[i]  = ld8(As + rowA + i * 1024 + cph[kc]);
#pragma unroll
            for (int j = 0; j < 4; j++) bfr[j] = ld8(Bs + rowB + j * 1024 + cph[kc]);
#pragma unroll
            for (int i = 0; i < 2; i++)
#pragma unroll
                for (int j = 0; j < 4; j++)
                    acc[i][j] = __builtin_amdgcn_mfma_f32_16x16x32_bf16(af[i], bfr[j], acc[i][j], 0, 0, 0);
        }
    }
#pragma unroll
    for (int i = 0; i < 2; i++)
#pragma unroll
        for (int j = 0; j < 4; j++) {
            int col = n0 + wc + j * 16 + l16;
#pragma unroll
            for (int r = 0; r < 4; r++) {
                int row = m0 + wr + i * 16 + quad * 4 + r;
                size_t idx = (size_t)bz * CCH * SSP + (size_t)row * SSP + col;
                Out[idx] = xres[idx] + acc[i][j][r] + bias[row];
            }
        }
}

// ---------------------------------------------------------------------------
// Flash attention v8 (round-10 proven, 153.6 us total): 256-thread blocks,
// 2 i-sets/wave, glls DMA double-buffer, 1 barrier/iter, max-free softmax.
__global__ __launch_bounds__(256, 2) void attn(const unsigned short* __restrict__ qkvt,
                                               const unsigned short* __restrict__ vt,
                                               unsigned short* __restrict__ ot) {
    int blk = blockIdx.x;                    // 512 blocks
    int xcd = blk & 7, jj = blk >> 3;        // 64 per XCD
    int bh = xcd * 8 + (jj >> 3);            // 8 heads per XCD (L2 locality)
    int i0 = (jj & 7) * 128;                 // 8 i-chunks of 128 rows
    int b = bh >> 3, h = bh & 7;

    __shared__ unsigned short KsD[2][64 * 64];      // [j][c] swizzled, 8 KB each
    __shared__ unsigned short VsD[2][64 * 64];      // [c][j] swizzled, 8 KB each
    __shared__ unsigned short PsD[4][2][16 * 64];   // [wave][iset] P^T, 16 KB

    int t = threadIdx.x, wave = t >> 6, lane = t & 63;
    int quad = lane >> 4, l16 = lane & 15;

    // Q fragments (B-operand) for the wave's two i-sets
    bf16x8 qf[2][2];   // [kc][iset]
#pragma unroll
    for (int is = 0; is < 2; is++) {
        const unsigned short* qp =
            qkvt + ((size_t)b * SSP + i0 + wave * 32 + is * 16 + l16) * O3 + h * DH + quad * 8;
        qf[0][is] = ld8(qp);
        qf[1][is] = ld8(qp + 32);
    }

    f32x4 Oa[2][4];
#pragma unroll
    for (int is = 0; is < 2; is++)
#pragma unroll
        for (int i = 0; i < 4; i++) Oa[is][i] = f32x4{0.f, 0.f, 0.f, 0.f};
    float l_acc[2] = {0.f, 0.f};

    // staging: 64-row tiles, 8 glls per tile, 2 per wave
    int lrow8 = lane >> 3, lc8 = ((lane & 7) - lrow8) & 7;
    const unsigned short* kga = qkvt + (size_t)b * SSP * O3 + CCH + h * DH;
    const unsigned short* vga = vt + (size_t)bh * DH * SSP;
    size_t koff[2];
    int voff[2], lds_off[2];
#pragma unroll
    for (int p = 0; p < 2; p++) {
        int row = wave * 16 + p * 8 + lrow8;
        koff[p] = (size_t)row * O3 + lc8 * 8;
        voff[p] = row * SSP + lc8 * 8;
        lds_off[p] = (wave * 16 + p * 8) * 64;
    }

    // prologue: stage tile 0 into buffer 0
#pragma unroll
    for (int p = 0; p < 2; p++) glls16(kga + koff[p], &KsD[0][lds_off[p]]);
#pragma unroll
    for (int p = 0; p < 2; p++) glls16(vga + voff[p], &VsD[0][lds_off[p]]);
    __syncthreads();

    for (int jb = 0; jb < 16; jb++) {
        int cur = jb & 1;
        if (jb < 15) {               // prefetch tile jb+1 (drains at barrier)
            int nxt = cur ^ 1;
            size_t j1k = (size_t)(jb + 1) * 64 * O3;
            int j1v = (jb + 1) * 64;
#pragma unroll
            for (int p = 0; p < 2; p++) glls16(kga + j1k + koff[p], &KsD[nxt][lds_off[p]]);
#pragma unroll
            for (int p = 0; p < 2; p++) glls16(vga + j1v + voff[p], &VsD[nxt][lds_off[p]]);
        }
        const unsigned short* ks = KsD[cur];
        const unsigned short* vs = VsD[cur];

        // load K fragments ONCE, feed both i-sets
        bf16x8 kf[2][4];
#pragma unroll
        for (int kc = 0; kc < 2; kc++)
#pragma unroll
            for (int tj = 0; tj < 4; tj++) {
                int row = tj * 16 + l16;
                kf[kc][tj] = ld8(ks + row * 64 + ((kc * 4 + quad + l16) & 7) * 8);
            }

        // S^T for both i-sets
        f32x4 sc0[4], sc1[4];
#pragma unroll
        for (int tj = 0; tj < 4; tj++) { sc0[tj] = f32x4{0.f,0.f,0.f,0.f}; sc1[tj] = f32x4{0.f,0.f,0.f,0.f}; }
#pragma unroll
        for (int kc = 0; kc < 2; kc++)
#pragma unroll
            for (int tj = 0; tj < 4; tj++) {
                sc0[tj] = __builtin_amdgcn_mfma_f32_16x16x32_bf16(kf[kc][tj], qf[kc][0], sc0[tj], 0, 0, 0);
                sc1[tj] = __builtin_amdgcn_mfma_f32_16x16x32_bf16(kf[kc][tj], qf[kc][1], sc1[tj], 0, 0, 0);
            }

        // max-free softmax + P pack for both i-sets (wave-local, no barrier)
        unsigned short* Ps0 = PsD[wave][0];
        unsigned short* Ps1 = PsD[wave][1];
#pragma unroll
        for (int tj = 0; tj < 4; tj++) {
#pragma unroll
            for (int r = 0; r < 4; r++) {
                float p0 = __builtin_amdgcn_exp2f(sc0[tj][r]);
                float p1 = __builtin_amdgcn_exp2f(sc1[tj][r]);
                sc0[tj][r] = p0; l_acc[0] += p0;
                sc1[tj][r] = p1; l_acc[1] += p1;
            }
            int phys = (tj * 2 + (quad >> 1) + l16) & 7;
            uint2 d0, d1;
            d0.x = pk2bf(sc0[tj][0], sc0[tj][1]);
            d0.y = pk2bf(sc0[tj][2], sc0[tj][3]);
            d1.x = pk2bf(sc1[tj][0], sc1[tj][1]);
            d1.y = pk2bf(sc1[tj][2], sc1[tj][3]);
            *(uint2*)(Ps0 + l16 * 64 + phys * 8 + (quad & 1) * 4) = d0;
            *(uint2*)(Ps1 + l16 * 64 + phys * 8 + (quad & 1) * 4) = d1;
        }

        // O^T += V^T . P^T; each vf load feeds both i-sets
#pragma unroll
        for (int kj = 0; kj < 2; kj++) {
            int pch = ((kj * 4 + quad + l16) & 7) * 8;
            bf16x8 pf0 = ld8(Ps0 + l16 * 64 + pch);
            bf16x8 pf1 = ld8(Ps1 + l16 * 64 + pch);
#pragma unroll
            for (int tc = 0; tc < 4; tc++) {
                int row = tc * 16 + l16;
                bf16x8 vf = ld8(vs + row * 64 + ((kj * 4 + quad + l16) & 7) * 8);
                Oa[0][tc] = __builtin_amdgcn_mfma_f32_16x16x32_bf16(vf, pf0, Oa[0][tc], 0, 0, 0);
                Oa[1][tc] = __builtin_amdgcn_mfma_f32_16x16x32_bf16(vf, pf1, Oa[1][tc], 0, 0, 0);
            }
        }

        __syncthreads();   // drains prefetch DMA + protects buffer swap
    }

    // deferred l-reduction + write-out per i-set
#pragma unroll
    for (int is = 0; is < 2; is++) {
        float l = l_acc[is];
        l += __shfl_xor(l, 16, 64);
        l += __shfl_xor(l, 32, 64);
        float rl = 1.f / l;
        int i = i0 + wave * 32 + is * 16 + l16;
        unsigned short* ob = ot + ((size_t)b * SSP + i) * CCH + h * DH;
#pragma unroll
        for (int tc = 0; tc < 4; tc++) {
            uint2 d;
            d.x = pk2bf(Oa[is][tc][0] * rl, Oa[is][tc][1] * rl);
            d.y = pk2bf(Oa[is][tc][2] * rl, Oa[is][tc][3] * rl);
            *(uint2*)(ob + tc * 16 + quad * 4) = d;
        }
    }
}

// ---------------------------------------------------------------------------
extern "C" void kernel_launch(void* const* d_in, const int* in_sizes, int n_in,
                              void* d_out, int out_size, void* d_ws, size_t ws_size,
                              hipStream_t stream) {
    const float* x      = (const float*)d_in[0];
    const float* gn_w   = (const float*)d_in[1];
    const float* gn_b   = (const float*)d_in[2];
    const float* qkv_w  = (const float*)d_in[3];
    const float* qkv_b  = (const float*)d_in[4];
    const float* proj_w = (const float*)d_in[5];
    const float* proj_b = (const float*)d_in[6];
    float* out = (float*)d_out;

    char* ws = (char*)d_ws;
    unsigned short* xnt   = (unsigned short*)(ws);                 // 8 MB  xn_t[b][s][c]
    unsigned short* qw_bf = (unsigned short*)(ws + 8388608);       // 1.5MB qkv_w bf16
    unsigned short* pw_bf = (unsigned short*)(ws + 9961472);       // 0.5MB proj_w bf16
    unsigned short* qkvt  = (unsigned short*)(ws + 10485760);      // 24 MB qkv_t[b][s][3C] (Q,K used)
    unsigned short* vt    = (unsigned short*)(ws + 35651584);      // 8 MB  v_t[bh*64+c][j]
    unsigned short* otb   = (unsigned short*)(ws + 44040192);      // 8 MB  o_t[b][s][c]

    gn_wconv<<<dim3(1280), dim3(256), 0, stream>>>(x, gn_w, gn_b, xnt,
                                                   qkv_w, qw_bf, 196608, proj_w, pw_bf);
    gemm_qkv<<<dim3(8, 12, 8), dim3(256), 0, stream>>>(xnt, qw_bf, qkv_b, qkvt, vt);
    attn<<<dim3(512), dim3(256), 0, stream>>>(qkvt, vt, otb);
    gemm_proj<<<dim3(8, 8, 8), dim3(256), 0, stream>>>(pw_bf, otb, proj_b, x, out);
}